// Round 5
// baseline (20955.043 us; speedup 1.0000x reference)
//
#include <hip/hip_runtime.h>
#include <hip/hip_bf16.h>

// ---------------------------------------------------------------------------
// LSTM  T=1024 B=64 IN=128 H=1024 OUT=128
// Round 5 (= Round 3/4 resubmit; GPU acquisition timed out both times,
// kernel has never run). Persistent cooperative kernel.
//   - W_hh|W_ih (K=1152) permuted per-wave and held in 144 VGPRs per wave
//   - 128 recurrence WGs (4 batch-groups x 32 CUs), c-state in registers
//   - h handoff via 64-slot ring + device-scope release/acquire flags
//   - 128 streaming out-worker WGs compute out(t) behind the recurrence
//   - fallback to proven multi-launch path if ws_size too small
// ---------------------------------------------------------------------------

using bf16x8 = __attribute__((ext_vector_type(8))) __bf16;
using f32x4  = __attribute__((ext_vector_type(4))) float;

__device__ __forceinline__ unsigned short f2bf(float f) {
    unsigned u = __builtin_bit_cast(unsigned, f);
    u = (u + 0x7FFFu + ((u >> 16) & 1u)) >> 16;
    return (unsigned short)u;
}

// ============================ persistent-path ws layout =====================
#define PS_XBF    0u            // [1024][64][128] bf16 : 16777216
#define PS_WPERM  16777216u     // [1024u][4g][1152k] bf16 : 9437184
#define PS_WOUT   26214400u     // [128][1024] bf16 : 262144
#define PS_BPERM  26476544u     // [1024][4] f32 : 16384
#define PS_HRING  26492928u     // [64][64][1024] bf16 : 8388608
#define PS_FLAGS  34881536u     // [1024][4] u32 : 16384
#define PS_TOTAL  34897920u

__global__ __launch_bounds__(256) void lstm_prep_ps(
    const float* __restrict__ in_seq, const float* __restrict__ h0,
    const float* __restrict__ W_ih,   const float* __restrict__ W_hh,
    const float* __restrict__ b_ih,   const float* __restrict__ b_hh,
    const float* __restrict__ W_out,
    unsigned short* __restrict__ xbf, unsigned short* __restrict__ wperm,
    unsigned short* __restrict__ woutb, float* __restrict__ bperm,
    unsigned short* __restrict__ hring, unsigned int* __restrict__ done)
{
    for (size_t i = (size_t)blockIdx.x * blockDim.x + threadIdx.x;
         i < 13312000u; i += (size_t)gridDim.x * blockDim.x) {
        if (i < 8388608u) {
            xbf[i] = f2bf(in_seq[i]);
        } else if (i < 13107200u) {
            size_t j = i - 8388608u;
            size_t r = j / 1152u, k = j - r * 1152u;   // r = u*4 + gate
            size_t u = r >> 2, gt = r & 3;
            float v = (k < 1024u) ? W_hh[(gt * 1024u + u) * 1024u + k]
                                  : W_ih[(gt * 1024u + u) * 128u + (k - 1024u)];
            wperm[j] = f2bf(v);
        } else if (i < 13238272u) {
            size_t j = i - 13107200u;
            woutb[j] = f2bf(W_out[j]);
        } else if (i < 13242368u) {
            size_t j = i - 13238272u;                   // j = u*4 + gate
            size_t u = j >> 2, gt = j & 3;
            bperm[j] = b_ih[gt * 1024u + u] + b_hh[gt * 1024u + u];
        } else if (i < 13307904u) {
            size_t j = i - 13242368u;
            hring[j] = f2bf(h0[j]);                     // ring slot 0 = h0
        } else {
            done[i - 13307904u] = 0u;                   // zero flags
        }
    }
}

__global__ __launch_bounds__(512) void lstm_persist(
    const unsigned short* __restrict__ xbf,
    const unsigned short* __restrict__ wperm,
    const unsigned short* __restrict__ woutb,
    const float* __restrict__ bperm,
    const float* __restrict__ b_out,
    const float* __restrict__ c0,
    unsigned short* __restrict__ hring,
    unsigned int* __restrict__ done,
    float* __restrict__ out)
{
    __shared__ unsigned short stage[2][16][32];   // h staging, dbuf by t&1
    const int tid = threadIdx.x;
    const int wv  = tid >> 6;        // wave 0..7
    const int l   = tid & 63;
    const int lk  = l >> 4;          // 0..3 (k-group / D-row group)
    const int c   = l & 15;          // A-row (batch) / B-col (gate-row)

    if (blockIdx.x < 128) {
        // ===================== recurrence block ============================
        const int g  = blockIdx.x & 3;      // batch group: rows [16g,16g+16)
        const int cu = blockIdx.x >> 2;     // 0..31, units [32cu,32cu+32)
        const int ubase = 32 * cu + 4 * wv; // this wave's first unit

        // W fragments: 36 x bf16x8 = 144 VGPRs, loaded once.
        bf16x8 wfrag[36];
        {
            const unsigned short* wrow = wperm + (size_t)(ubase * 4 + c) * 1152u + lk * 8;
#pragma unroll
            for (int kk = 0; kk < 36; ++kk)
                wfrag[kk] = *(const bf16x8*)(wrow + kk * 32);
        }
        const float bias = bperm[ubase * 4 + c];

        // cell state in registers: lanes with (c&3)==0 own unit ubase+(c>>2),
        // batches 16g + 4*lk + s.
        float cst[4];
        {
            const int ug = ubase + (c >> 2);
#pragma unroll
            for (int s = 0; s < 4; ++s)
                cst[s] = c0[(16 * g + 4 * lk + s) * 1024 + ug];
        }

        for (int t = 0; t < 1024; ++t) {
            if (t > 0) {
                const unsigned idx = (unsigned)(t - 1) * 4u + (unsigned)g;
                if (tid == 0) {
                    unsigned v; int it = 0;
                    do {
                        v = __hip_atomic_load(&done[idx], __ATOMIC_RELAXED,
                                              __HIP_MEMORY_SCOPE_AGENT);
                        if (v >= 32u) break;
                        __builtin_amdgcn_s_sleep(2);
                    } while (++it < (1 << 23));
                }
                __syncthreads();
                (void)__hip_atomic_load(&done[idx], __ATOMIC_ACQUIRE,
                                        __HIP_MEMORY_SCOPE_AGENT);
            }

            const unsigned short* hrow = hring + (size_t)(t & 63) * 65536u
                                       + (size_t)(16 * g + c) * 1024u + lk * 8;
            const unsigned short* xrow = xbf + ((size_t)t * 64u + 16 * g + c) * 128u + lk * 8;

            f32x4 acc[4];
#pragma unroll
            for (int s = 0; s < 4; ++s) acc[s] = f32x4{0.f, 0.f, 0.f, 0.f};
#pragma unroll
            for (int kk = 0; kk < 36; ++kk) {
                bf16x8 af = (kk < 32) ? *(const bf16x8*)(hrow + kk * 32)
                                      : *(const bf16x8*)(xrow + (kk - 32) * 32);
                acc[kk & 3] = __builtin_amdgcn_mfma_f32_16x16x32_bf16(af, wfrag[kk], acc[kk & 3], 0, 0, 0);
            }
            f32x4 gsum = (acc[0] + acc[1]) + (acc[2] + acc[3]);
#pragma unroll
            for (int s = 0; s < 4; ++s) gsum[s] += bias;

            // gather f,g,o (cols c+1..c+3) into the i-lanes (c%4==0)
            float fv[4], gv[4], ov[4];
            const int base = l & 48;
#pragma unroll
            for (int s = 0; s < 4; ++s) {
                fv[s] = __shfl(gsum[s], base | ((c + 1) & 15));
                gv[s] = __shfl(gsum[s], base | ((c + 2) & 15));
                ov[s] = __shfl(gsum[s], base | ((c + 3) & 15));
            }
            if ((c & 3) == 0) {
                const int ul = wv * 4 + (c >> 2);    // unit-local 0..31
#pragma unroll
                for (int s = 0; s < 4; ++s) {
                    float i_ = 1.f / (1.f + __expf(-gsum[s]));
                    float f_ = 1.f / (1.f + __expf(-fv[s]));
                    float g_ = 1.f - 2.f / (__expf(2.f * gv[s]) + 1.f);
                    float o_ = 1.f / (1.f + __expf(-ov[s]));
                    float cn = f_ * cst[s] + i_ * g_;
                    cst[s] = cn;
                    float th = 1.f - 2.f / (__expf(2.f * cn) + 1.f);
                    stage[t & 1][4 * lk + s][ul] = f2bf(o_ * th);
                }
            }
            __syncthreads();
            if (wv == 0) {
                // wave0 stores the CU's [16b][32u] chunk, then releases flag.
                bf16x8 hv = *(const bf16x8*)&stage[t & 1][l >> 2][8 * (l & 3)];
                *(bf16x8*)(hring + (size_t)((t + 1) & 63) * 65536u
                           + (size_t)(16 * g + (l >> 2)) * 1024u
                           + 32 * cu + 8 * (l & 3)) = hv;
                if (l == 0)
                    __hip_atomic_fetch_add(&done[(unsigned)t * 4u + (unsigned)g], 1u,
                                           __ATOMIC_RELEASE, __HIP_MEMORY_SCOPE_AGENT);
            }
        }
    } else {
        // ===================== streaming out-worker ========================
        const int ow = blockIdx.x - 128;     // handles t = ow + 128*rep
        bf16x8 wof[32];
        {
            const unsigned short* wr = woutb + (size_t)(16 * wv + c) * 1024u + lk * 8;
#pragma unroll
            for (int kk = 0; kk < 32; ++kk)
                wof[kk] = *(const bf16x8*)(wr + kk * 32);
        }
        const float bo = b_out[16 * wv + c];

        for (int rep = 0; rep < 8; ++rep) {
            const int t = ow + rep * 128;
            if (tid == 0) {
#pragma unroll
                for (int g4 = 0; g4 < 4; ++g4) {
                    unsigned v; int it = 0;
                    do {
                        v = __hip_atomic_load(&done[(unsigned)t * 4u + g4], __ATOMIC_RELAXED,
                                              __HIP_MEMORY_SCOPE_AGENT);
                        if (v >= 32u) break;
                        __builtin_amdgcn_s_sleep(8);
                    } while (++it < (1 << 23));
                }
            }
            __syncthreads();
#pragma unroll
            for (int g4 = 0; g4 < 4; ++g4)
                (void)__hip_atomic_load(&done[(unsigned)t * 4u + g4], __ATOMIC_ACQUIRE,
                                        __HIP_MEMORY_SCOPE_AGENT);

            const unsigned short* hb = hring + (size_t)((t + 1) & 63) * 65536u;
            f32x4 acc[4];
#pragma unroll
            for (int mt = 0; mt < 4; ++mt) acc[mt] = f32x4{0.f, 0.f, 0.f, 0.f};
#pragma unroll
            for (int kk = 0; kk < 32; ++kk) {
#pragma unroll
                for (int mt = 0; mt < 4; ++mt) {
                    bf16x8 af = *(const bf16x8*)(hb + (size_t)(16 * mt + c) * 1024u + kk * 32 + lk * 8);
                    acc[mt] = __builtin_amdgcn_mfma_f32_16x16x32_bf16(af, wof[kk], acc[mt], 0, 0, 0);
                }
            }
#pragma unroll
            for (int mt = 0; mt < 4; ++mt)
#pragma unroll
                for (int s = 0; s < 4; ++s)
                    out[((size_t)t * 64u + 16 * mt + 4 * lk + s) * 128u + 16 * wv + c]
                        = acc[mt][s] + bo;
        }
    }
}

// ======================= fallback multi-launch path (proven) ================
#define OFF_XBF   0u
#define OFF_WCAT  16777216u
#define OFF_WOUT  26214400u
#define OFF_BSUM  26476544u
#define OFF_HBUF  26492928u
#define OFF_CST   26755072u

__global__ __launch_bounds__(256) void lstm_prep(
    const float* __restrict__ in_seq, const float* __restrict__ h0,
    const float* __restrict__ c0,     const float* __restrict__ W_ih,
    const float* __restrict__ W_hh,   const float* __restrict__ b_ih,
    const float* __restrict__ b_hh,   const float* __restrict__ W_out,
    unsigned short* __restrict__ xbf, unsigned short* __restrict__ wcat,
    unsigned short* __restrict__ woutb, float* __restrict__ bsum,
    unsigned short* __restrict__ hbuf, float* __restrict__ cstate)
{
    for (size_t i = (size_t)blockIdx.x * blockDim.x + threadIdx.x;
         i < 13373440u; i += (size_t)gridDim.x * blockDim.x) {
        if (i < 8388608u) {
            xbf[i] = f2bf(in_seq[i]);
        } else if (i < 13107200u) {
            size_t j = i - 8388608u;
            size_t r = j / 1152u, k = j - r * 1152u;
            float v = (k < 1024u) ? W_hh[r * 1024u + k] : W_ih[r * 128u + (k - 1024u)];
            wcat[j] = f2bf(v);
        } else if (i < 13238272u) {
            size_t j = i - 13107200u;
            woutb[j] = f2bf(W_out[j]);
        } else if (i < 13242368u) {
            size_t j = i - 13238272u;
            bsum[j] = b_ih[j] + b_hh[j];
        } else if (i < 13307904u) {
            size_t j = i - 13242368u;
            hbuf[j] = f2bf(h0[j]);
        } else {
            size_t j = i - 13307904u;
            cstate[j] = c0[j];
        }
    }
}

__global__ __launch_bounds__(256) void lstm_step(
    const unsigned short* __restrict__ xbf,
    const unsigned short* __restrict__ wcat,
    const unsigned short* __restrict__ woutb,
    const float* __restrict__ bsum,
    const float* __restrict__ bout,
    unsigned short* __restrict__ hbuf,
    float* __restrict__ cstate,
    float* __restrict__ out,
    int t)
{
    __shared__ float red[4096];
    const int tid = threadIdx.x;
    const int w   = tid >> 6;
    const int l   = tid & 63;
    const int l4  = l >> 4;
    const int l15 = l & 15;
    const int rb  = t & 1;
    const int wb  = rb ^ 1;

    if (blockIdx.x < 256) {
        if (t >= 1024) return;
        const int p = blockIdx.x >> 6;
        const int q = blockIdx.x & 63;
        const int arow = 16 * p + l15;

        const unsigned short* hrow = hbuf + (size_t)rb * 65536u + (size_t)arow * 1024u;
        const unsigned short* xrow = xbf + ((size_t)t * 64u + arow) * 128u;
        const unsigned short* wrow0 = wcat + (size_t)(16 * q + l15) * 1152u;

        f32x4 acc0 = {0.f, 0.f, 0.f, 0.f}, acc1 = acc0, acc2 = acc0, acc3 = acc0;
        const int kbase = w * 288;

#pragma unroll
        for (int kk = 0; kk < 9; ++kk) {
            const int k0   = kbase + kk * 32;
            const int koff = k0 + l4 * 8;
            bf16x8 a;
            if (k0 < 1024) a = *(const bf16x8*)(hrow + koff);
            else           a = *(const bf16x8*)(xrow + (koff - 1024));
            const size_t wo = (size_t)koff;
            bf16x8 b0 = *(const bf16x8*)(wrow0 + wo);
            bf16x8 b1 = *(const bf16x8*)(wrow0 + wo + 1024u * 1152u);
            bf16x8 b2 = *(const bf16x8*)(wrow0 + wo + 2048u * 1152u);
            bf16x8 b3 = *(const bf16x8*)(wrow0 + wo + 3072u * 1152u);
            acc0 = __builtin_amdgcn_mfma_f32_16x16x32_bf16(a, b0, acc0, 0, 0, 0);
            acc1 = __builtin_amdgcn_mfma_f32_16x16x32_bf16(a, b1, acc1, 0, 0, 0);
            acc2 = __builtin_amdgcn_mfma_f32_16x16x32_bf16(a, b2, acc2, 0, 0, 0);
            acc3 = __builtin_amdgcn_mfma_f32_16x16x32_bf16(a, b3, acc3, 0, 0, 0);
        }

#pragma unroll
        for (int s = 0; s < 4; ++s) {
            f32x4 vv = {acc0[s], acc1[s], acc2[s], acc3[s]};
            const int a16 = s * 256 + (((l * 4) + w) ^ (l & 7));
            *(f32x4*)((char*)red + (size_t)a16 * 16u) = vv;
        }
        __syncthreads();

        f32x4 gv = {0.f, 0.f, 0.f, 0.f};
#pragma unroll
        for (int v = 0; v < 4; ++v) {
            const int a16 = w * 256 + (((l * 4) + v) ^ (l & 7));
            gv += *(const f32x4*)((const char*)red + (size_t)a16 * 16u);
        }

        const int u = 16 * q + l15;
        const int b = 16 * p + 4 * l4 + w;
        float gi = gv[0] + bsum[u];
        float gf = gv[1] + bsum[1024 + u];
        float gg = gv[2] + bsum[2048 + u];
        float go = gv[3] + bsum[3072 + u];
        float i_ = 1.f / (1.f + __expf(-gi));
        float f_ = 1.f / (1.f + __expf(-gf));
        float g_ = 1.f - 2.f / (__expf(2.f * gg) + 1.f);
        float o_ = 1.f / (1.f + __expf(-go));
        float c  = cstate[b * 1024 + u];
        float cn = f_ * c + i_ * g_;
        cstate[b * 1024 + u] = cn;
        float th = 1.f - 2.f / (__expf(2.f * cn) + 1.f);
        hbuf[(size_t)wb * 65536u + (size_t)b * 1024u + u] = f2bf(o_ * th);
    } else {
        if (t < 1) return;
        const int j = blockIdx.x - 256;
        const int p = j >> 3;
        const int n = j & 7;
        const unsigned short* hrow = hbuf + (size_t)rb * 65536u + (size_t)(16 * p + l15) * 1024u;
        const unsigned short* wrow = woutb + (size_t)(16 * n + l15) * 1024u;

        f32x4 acc = {0.f, 0.f, 0.f, 0.f};
#pragma unroll
        for (int kk = 0; kk < 8; ++kk) {
            const int koff = w * 256 + kk * 32 + l4 * 8;
            bf16x8 a  = *(const bf16x8*)(hrow + koff);
            bf16x8 bb = *(const bf16x8*)(wrow + koff);
            acc = __builtin_amdgcn_mfma_f32_16x16x32_bf16(a, bb, acc, 0, 0, 0);
        }
#pragma unroll
        for (int s = 0; s < 4; ++s) {
            const int a16 = s * 256 + (((l * 4) + w) ^ (l & 7));
            ((float*)red)[(size_t)a16 * 4u] = acc[s];
        }
        __syncthreads();
        float sum = 0.f;
#pragma unroll
        for (int v = 0; v < 4; ++v) {
            const int a16 = w * 256 + (((l * 4) + v) ^ (l & 7));
            sum += ((const float*)red)[(size_t)a16 * 4u];
        }
        const int o = 16 * n + l15;
        const int b = 16 * p + 4 * l4 + w;
        out[((size_t)(t - 1) * 64u + b) * 128u + o] = sum + bout[o];
    }
}

// ============================== launcher ====================================
extern "C" void kernel_launch(void* const* d_in, const int* in_sizes, int n_in,
                              void* d_out, int out_size, void* d_ws, size_t ws_size,
                              hipStream_t stream) {
    const float* in_seq = (const float*)d_in[0];
    const float* h0     = (const float*)d_in[1];
    const float* c0     = (const float*)d_in[2];
    const float* W_ih   = (const float*)d_in[3];
    const float* W_hh   = (const float*)d_in[4];
    const float* b_ih   = (const float*)d_in[5];
    const float* b_hh   = (const float*)d_in[6];
    const float* W_out  = (const float*)d_in[7];
    const float* b_out  = (const float*)d_in[8];
    char* ws = (char*)d_ws;
    float* out = (float*)d_out;

    if (ws_size >= (size_t)PS_TOTAL) {
        // ---------------- persistent cooperative path ----------------------
        unsigned short* xbf   = (unsigned short*)(ws + PS_XBF);
        unsigned short* wperm = (unsigned short*)(ws + PS_WPERM);
        unsigned short* woutb = (unsigned short*)(ws + PS_WOUT);
        float*          bperm = (float*)(ws + PS_BPERM);
        unsigned short* hring = (unsigned short*)(ws + PS_HRING);
        unsigned int*   done  = (unsigned int*)(ws + PS_FLAGS);

        lstm_prep_ps<<<2048, 256, 0, stream>>>(in_seq, h0, W_ih, W_hh, b_ih, b_hh,
                                               W_out, xbf, wperm, woutb, bperm,
                                               hring, done);
        void* args[] = { &xbf, &wperm, &woutb, &bperm, (void*)&b_out, (void*)&c0,
                         &hring, &done, &out };
        hipLaunchCooperativeKernel((const void*)lstm_persist, dim3(256), dim3(512),
                                   args, 0, stream);
    } else {
        // ---------------- fallback: proven multi-launch path ---------------
        unsigned short* xbf   = (unsigned short*)(ws + OFF_XBF);
        unsigned short* wcat  = (unsigned short*)(ws + OFF_WCAT);
        unsigned short* woutb = (unsigned short*)(ws + OFF_WOUT);
        float*          bsum  = (float*)(ws + OFF_BSUM);
        unsigned short* hbuf  = (unsigned short*)(ws + OFF_HBUF);
        float*          cst   = (float*)(ws + OFF_CST);

        lstm_prep<<<2048, 256, 0, stream>>>(in_seq, h0, c0, W_ih, W_hh, b_ih, b_hh,
                                            W_out, xbf, wcat, woutb, bsum, hbuf, cst);
        for (int t = 0; t <= 1024; ++t) {
            lstm_step<<<288, 256, 0, stream>>>(xbf, wcat, woutb, bsum, b_out,
                                               hbuf, cst, out, t);
        }
    }
}

// Round 7
// 7086.111 us; speedup vs baseline: 2.9572x; 2.9572x over previous
//
#include <hip/hip_runtime.h>
#include <hip/hip_bf16.h>

// ---------------------------------------------------------------------------
// LSTM  T=1024 B=64 IN=128 H=1024 OUT=128
// Round 7 (= Round 6 resubmit; GPU acquisition timed out, kernel never ran).
// Persistent kernel, protocol rebuilt after R5 post-mortem.
//   R5 failure: (1) VGPR capped 128 -> weight spills; (2) agent acq/rel per
//   step -> full L2 writeback+invalidate storms (20.5us/step).
//   Now: relaxed LLC atomics for h-ring (no cache maintenance), manual
//   vmcnt ordering, launch_bounds(512,2) for 256-VGPR budget,
//   swapped MFMA orientation (A=W,B=h) -> gates land in-lane,
//   8-way split-K + LDS reduce -> minimal h traffic.
// ---------------------------------------------------------------------------

using bf16x8 = __attribute__((ext_vector_type(8))) __bf16;
using f32x4  = __attribute__((ext_vector_type(4))) float;

__device__ __forceinline__ unsigned short f2bf(float f) {
    unsigned u = __builtin_bit_cast(unsigned, f);
    u = (u + 0x7FFFu + ((u >> 16) & 1u)) >> 16;
    return (unsigned short)u;
}

#define AT_LD(p)    __hip_atomic_load((p), __ATOMIC_RELAXED, __HIP_MEMORY_SCOPE_AGENT)
#define AT_ST(p, v) __hip_atomic_store((p), (v), __ATOMIC_RELAXED, __HIP_MEMORY_SCOPE_AGENT)

__device__ __forceinline__ bool waitflag(unsigned* f, unsigned target) {
    for (int it = 0; it < (1 << 16); ++it) {
        if (AT_LD(f) >= target) return true;
        __builtin_amdgcn_s_sleep(2);
    }
    return false;   // deadlock latch: fail fast with wrong answer, never hang
}

// ============================ persistent-path ws layout =====================
#define PS_XBF    0u            // [1024][64][128] bf16 : 16777216
#define PS_WPERM  16777216u     // [4096 rows=(u*4+gate)][1152] bf16 : 9437184
#define PS_WOUT   26214400u     // [128][1024] bf16 : 262144
#define PS_BPERM  26476544u     // [1024][4] f32 : 16384
#define PS_HRING  26492928u     // [64][64][1024] bf16 : 8388608
#define PS_FLAGS  34881536u     // [1024][4] u32 : 16384
#define PS_TOTAL  34897920u

__global__ __launch_bounds__(256) void lstm_prep_ps(
    const float* __restrict__ in_seq, const float* __restrict__ h0,
    const float* __restrict__ W_ih,   const float* __restrict__ W_hh,
    const float* __restrict__ b_ih,   const float* __restrict__ b_hh,
    const float* __restrict__ W_out,
    unsigned short* __restrict__ xbf, unsigned short* __restrict__ wperm,
    unsigned short* __restrict__ woutb, float* __restrict__ bperm,
    unsigned short* __restrict__ hring, unsigned int* __restrict__ done)
{
    for (size_t i = (size_t)blockIdx.x * blockDim.x + threadIdx.x;
         i < 13312000u; i += (size_t)gridDim.x * blockDim.x) {
        if (i < 8388608u) {
            xbf[i] = f2bf(in_seq[i]);
        } else if (i < 13107200u) {
            size_t j = i - 8388608u;
            size_t r = j / 1152u, k = j - r * 1152u;   // r = u*4 + gate
            size_t u = r >> 2, gt = r & 3;
            float v = (k < 1024u) ? W_hh[(gt * 1024u + u) * 1024u + k]
                                  : W_ih[(gt * 1024u + u) * 128u + (k - 1024u)];
            wperm[j] = f2bf(v);
        } else if (i < 13238272u) {
            size_t j = i - 13107200u;
            woutb[j] = f2bf(W_out[j]);
        } else if (i < 13242368u) {
            size_t j = i - 13238272u;                   // j = u*4 + gate
            size_t u = j >> 2, gt = j & 3;
            bperm[j] = b_ih[gt * 1024u + u] + b_hh[gt * 1024u + u];
        } else if (i < 13307904u) {
            size_t j = i - 13242368u;
            hring[j] = f2bf(h0[j]);                     // ring slot 0 = h0
        } else {
            done[i - 13307904u] = 0u;                   // zero flags
        }
    }
}

__global__ __launch_bounds__(512, 2) void lstm_persist(
    const unsigned short* __restrict__ xbf,
    const unsigned short* __restrict__ wperm,
    const unsigned short* __restrict__ woutb,
    const float* __restrict__ bperm,
    const float* __restrict__ b_out,
    const float* __restrict__ c0,
    unsigned short* __restrict__ hring,
    unsigned int* __restrict__ done,
    float* __restrict__ out)
{
    __shared__ f32x4 red[8][8][64];     // 64 KiB split-K reduce buffer
    const int tid = threadIdx.x;
    const int wv  = tid >> 6;           // wave 0..7
    const int l   = tid & 63;
    const int lk  = l >> 4;             // 0..3 : k-subgroup / D row-group
    const int c   = l & 15;             // A row (gate-row) / B col (batch)
    unsigned* ring32 = (unsigned*)hring;

    if (blockIdx.x < 128) {
        // ===================== recurrence block ============================
        const int g    = blockIdx.x & 3;    // batch rows [16g,16g+16)
        const int rank = blockIdx.x >> 2;   // units [32*rank, 32*rank+32)
        const int nck  = (wv < 4) ? 5 : 4;  // K-chunks (of 32) this wave owns
        const int ck0  = (wv < 4) ? wv * 5 : 20 + (wv - 4) * 4;

        // A-operand weights in registers: wfA[chunk][tile], <=160 VGPR.
        // wperm row (global) = 128*rank + 16*r + c  <->  unit*4+gate.
        bf16x8 wfA[5][8];
#pragma unroll
        for (int ci = 0; ci < 5; ++ci) {
            if (ci < nck) {
                const int kk = ck0 + ci;
#pragma unroll
                for (int r = 0; r < 8; ++r)
                    wfA[ci][r] = *(const bf16x8*)(wperm
                        + (size_t)(128 * rank + 16 * r + c) * 1152u
                        + (size_t)(kk * 32 + lk * 8));
            }
        }
        // Reducer identity: wave wv reduces tile wv; lane (c,lk) owns
        // unit = 32*rank + 4*wv + lk, batch = 16g + c, gates in vector slots.
        const int myu = 32 * rank + 4 * wv + lk;
        const f32x4 bias = *(const f32x4*)(bperm + (size_t)myu * 4u);
        float cst = c0[(size_t)(16 * g + c) * 1024u + myu];
        bool dead = false;

        for (int t = 0; t < 1024; ++t) {
            if (t > 0) {
                if (tid == 0 && !dead)
                    dead = !waitflag(&done[(unsigned)(t - 1) * 4u + g], 32u);
                __syncthreads();
            }

            f32x4 acc[8];
#pragma unroll
            for (int r = 0; r < 8; ++r) acc[r] = f32x4{0.f, 0.f, 0.f, 0.f};

#pragma unroll
            for (int ci = 0; ci < 5; ++ci) {
                if (ci < nck) {
                    const int kk = ck0 + ci;
                    bf16x8 bf;
                    if (kk < 32) {
                        // h(t-1) via relaxed LLC atomics (no L1/L2 staleness)
                        const unsigned* hp = ring32 + (size_t)(t & 63) * 32768u
                                           + (size_t)(16 * g + c) * 512u
                                           + (size_t)(kk * 16 + lk * 4);
                        union { unsigned u[4]; bf16x8 v; } cv;
                        cv.u[0] = AT_LD(hp + 0); cv.u[1] = AT_LD(hp + 1);
                        cv.u[2] = AT_LD(hp + 2); cv.u[3] = AT_LD(hp + 3);
                        bf = cv.v;
                    } else {
                        // x part: read-only, plain cached loads
                        bf = *(const bf16x8*)(xbf
                            + ((size_t)t * 64u + 16 * g + c) * 128u
                            + (size_t)((kk - 32) * 32 + lk * 8));
                    }
#pragma unroll
                    for (int r = 0; r < 8; ++r)
                        acc[r] = __builtin_amdgcn_mfma_f32_16x16x32_bf16(
                                     wfA[ci][r], bf, acc[r], 0, 0, 0);
                }
            }

            // split-K reduce: wave wv sums tile wv across the 8 partials
#pragma unroll
            for (int r = 0; r < 8; ++r) red[wv][r][l] = acc[r];
            __syncthreads();
            f32x4 sv = red[0][wv][l];
#pragma unroll
            for (int v = 1; v < 8; ++v) sv += red[v][wv][l];
            sv += bias;

            // gates are in-lane: s0=i s1=f s2=g s3=o for (myu, batch 16g+c)
            float i_ = 1.f / (1.f + __expf(-sv[0]));
            float f_ = 1.f / (1.f + __expf(-sv[1]));
            float g_ = 1.f - 2.f / (__expf(2.f * sv[2]) + 1.f);
            float o_ = 1.f / (1.f + __expf(-sv[3]));
            float cn = f_ * cst + i_ * g_;
            cst = cn;
            float th = 1.f - 2.f / (__expf(2.f * cn) + 1.f);
            unsigned hb = f2bf(o_ * th);

            // pack unit pairs (lk even | lk odd) into a dword, store to ring
            unsigned other = ((unsigned)__shfl_xor((int)hb, 16, 64)) & 0xFFFFu;
            if ((lk & 1) == 0) {
                AT_ST(ring32 + (size_t)((t + 1) & 63) * 32768u
                             + (size_t)(16 * g + c) * 512u + (myu >> 1),
                      (hb & 0xFFFFu) | (other << 16));
            }
            asm volatile("s_waitcnt vmcnt(0)" ::: "memory");
            __builtin_amdgcn_sched_barrier(0);
            __syncthreads();
            if (tid == 0)
                __hip_atomic_fetch_add(&done[(unsigned)t * 4u + g], 1u,
                                       __ATOMIC_RELAXED, __HIP_MEMORY_SCOPE_AGENT);
        }
    } else {
        // ===================== streaming out-worker ========================
        const int ow = blockIdx.x - 128;    // handles t = ow + 128*rep
        bf16x8 wofB[32];                    // B-operand: out-col = 16*wv + c
        {
            const unsigned short* wr = woutb + (size_t)(16 * wv + c) * 1024u + lk * 8;
#pragma unroll
            for (int kk = 0; kk < 32; ++kk)
                wofB[kk] = *(const bf16x8*)(wr + kk * 32);
        }
        const float bo = b_out[16 * wv + c];
        bool dead = false;

        for (int rep = 0; rep < 8; ++rep) {
            const int t = ow + 128 * rep;
            if (tid == 0 && !dead) {
#pragma unroll
                for (int g4 = 0; g4 < 4; ++g4)
                    if (!waitflag(&done[(unsigned)t * 4u + g4], 32u)) dead = true;
            }
            __syncthreads();

            const unsigned* hb0 = ring32 + (size_t)((t + 1) & 63) * 32768u;
            f32x4 acc[4];
#pragma unroll
            for (int mt = 0; mt < 4; ++mt) acc[mt] = f32x4{0.f, 0.f, 0.f, 0.f};
#pragma unroll 4
            for (int kk = 0; kk < 32; ++kk) {
#pragma unroll
                for (int mt = 0; mt < 4; ++mt) {
                    const unsigned* hp = hb0 + (size_t)(16 * mt + c) * 512u
                                       + (size_t)(kk * 16 + lk * 4);
                    union { unsigned u[4]; bf16x8 v; } cv;
                    cv.u[0] = AT_LD(hp + 0); cv.u[1] = AT_LD(hp + 1);
                    cv.u[2] = AT_LD(hp + 2); cv.u[3] = AT_LD(hp + 3);
                    acc[mt] = __builtin_amdgcn_mfma_f32_16x16x32_bf16(
                                  cv.v, wofB[kk], acc[mt], 0, 0, 0);
                }
            }
#pragma unroll
            for (int mt = 0; mt < 4; ++mt)
#pragma unroll
                for (int s = 0; s < 4; ++s)
                    out[((size_t)t * 64u + 16 * mt + 4 * lk + s) * 128u + 16 * wv + c]
                        = acc[mt][s] + bo;
        }
    }
}

// ======================= fallback multi-launch path (proven, R2) ============
#define OFF_XBF   0u
#define OFF_WCAT  16777216u
#define OFF_WOUT  26214400u
#define OFF_BSUM  26476544u
#define OFF_HBUF  26492928u
#define OFF_CST   26755072u

__global__ __launch_bounds__(256) void lstm_prep(
    const float* __restrict__ in_seq, const float* __restrict__ h0,
    const float* __restrict__ c0,     const float* __restrict__ W_ih,
    const float* __restrict__ W_hh,   const float* __restrict__ b_ih,
    const float* __restrict__ b_hh,   const float* __restrict__ W_out,
    unsigned short* __restrict__ xbf, unsigned short* __restrict__ wcat,
    unsigned short* __restrict__ woutb, float* __restrict__ bsum,
    unsigned short* __restrict__ hbuf, float* __restrict__ cstate)
{
    for (size_t i = (size_t)blockIdx.x * blockDim.x + threadIdx.x;
         i < 13373440u; i += (size_t)gridDim.x * blockDim.x) {
        if (i < 8388608u) {
            xbf[i] = f2bf(in_seq[i]);
        } else if (i < 13107200u) {
            size_t j = i - 8388608u;
            size_t r = j / 1152u, k = j - r * 1152u;
            float v = (k < 1024u) ? W_hh[r * 1024u + k] : W_ih[r * 128u + (k - 1024u)];
            wcat[j] = f2bf(v);
        } else if (i < 13238272u) {
            size_t j = i - 13107200u;
            woutb[j] = f2bf(W_out[j]);
        } else if (i < 13242368u) {
            size_t j = i - 13238272u;
            bsum[j] = b_ih[j] + b_hh[j];
        } else if (i < 13307904u) {
            size_t j = i - 13242368u;
            hbuf[j] = f2bf(h0[j]);
        } else {
            size_t j = i - 13307904u;
            cstate[j] = c0[j];
        }
    }
}

__global__ __launch_bounds__(256) void lstm_step(
    const unsigned short* __restrict__ xbf,
    const unsigned short* __restrict__ wcat,
    const unsigned short* __restrict__ woutb,
    const float* __restrict__ bsum,
    const float* __restrict__ bout,
    unsigned short* __restrict__ hbuf,
    float* __restrict__ cstate,
    float* __restrict__ out,
    int t)
{
    __shared__ float red[4096];
    const int tid = threadIdx.x;
    const int w   = tid >> 6;
    const int l   = tid & 63;
    const int l4  = l >> 4;
    const int l15 = l & 15;
    const int rb  = t & 1;
    const int wb  = rb ^ 1;

    if (blockIdx.x < 256) {
        if (t >= 1024) return;
        const int p = blockIdx.x >> 6;
        const int q = blockIdx.x & 63;
        const int arow = 16 * p + l15;

        const unsigned short* hrow = hbuf + (size_t)rb * 65536u + (size_t)arow * 1024u;
        const unsigned short* xrow = xbf + ((size_t)t * 64u + arow) * 128u;
        const unsigned short* wrow0 = wcat + (size_t)(16 * q + l15) * 1152u;

        f32x4 acc0 = {0.f, 0.f, 0.f, 0.f}, acc1 = acc0, acc2 = acc0, acc3 = acc0;
        const int kbase = w * 288;

#pragma unroll
        for (int kk = 0; kk < 9; ++kk) {
            const int k0   = kbase + kk * 32;
            const int koff = k0 + l4 * 8;
            bf16x8 a;
            if (k0 < 1024) a = *(const bf16x8*)(hrow + koff);
            else           a = *(const bf16x8*)(xrow + (koff - 1024));
            const size_t wo = (size_t)koff;
            bf16x8 b0 = *(const bf16x8*)(wrow0 + wo);
            bf16x8 b1 = *(const bf16x8*)(wrow0 + wo + 1024u * 1152u);
            bf16x8 b2 = *(const bf16x8*)(wrow0 + wo + 2048u * 1152u);
            bf16x8 b3 = *(const bf16x8*)(wrow0 + wo + 3072u * 1152u);
            acc0 = __builtin_amdgcn_mfma_f32_16x16x32_bf16(a, b0, acc0, 0, 0, 0);
            acc1 = __builtin_amdgcn_mfma_f32_16x16x32_bf16(a, b1, acc1, 0, 0, 0);
            acc2 = __builtin_amdgcn_mfma_f32_16x16x32_bf16(a, b2, acc2, 0, 0, 0);
            acc3 = __builtin_amdgcn_mfma_f32_16x16x32_bf16(a, b3, acc3, 0, 0, 0);
        }

#pragma unroll
        for (int s = 0; s < 4; ++s) {
            f32x4 vv = {acc0[s], acc1[s], acc2[s], acc3[s]};
            const int a16 = s * 256 + (((l * 4) + w) ^ (l & 7));
            *(f32x4*)((char*)red + (size_t)a16 * 16u) = vv;
        }
        __syncthreads();

        f32x4 gv = {0.f, 0.f, 0.f, 0.f};
#pragma unroll
        for (int v = 0; v < 4; ++v) {
            const int a16 = w * 256 + (((l * 4) + v) ^ (l & 7));
            gv += *(const f32x4*)((const char*)red + (size_t)a16 * 16u);
        }

        const int u = 16 * q + l15;
        const int b = 16 * p + 4 * l4 + w;
        float gi = gv[0] + bsum[u];
        float gf = gv[1] + bsum[1024 + u];
        float gg = gv[2] + bsum[2048 + u];
        float go = gv[3] + bsum[3072 + u];
        float i_ = 1.f / (1.f + __expf(-gi));
        float f_ = 1.f / (1.f + __expf(-gf));
        float g_ = 1.f - 2.f / (__expf(2.f * gg) + 1.f);
        float o_ = 1.f / (1.f + __expf(-go));
        float c  = cstate[b * 1024 + u];
        float cn = f_ * c + i_ * g_;
        cstate[b * 1024 + u] = cn;
        float th = 1.f - 2.f / (__expf(2.f * cn) + 1.f);
        hbuf[(size_t)wb * 65536u + (size_t)b * 1024u + u] = f2bf(o_ * th);
    } else {
        if (t < 1) return;
        const int j = blockIdx.x - 256;
        const int p = j >> 3;
        const int n = j & 7;
        const unsigned short* hrow = hbuf + (size_t)rb * 65536u + (size_t)(16 * p + l15) * 1024u;
        const unsigned short* wrow = woutb + (size_t)(16 * n + l15) * 1024u;

        f32x4 acc = {0.f, 0.f, 0.f, 0.f};
#pragma unroll
        for (int kk = 0; kk < 8; ++kk) {
            const int koff = w * 256 + kk * 32 + l4 * 8;
            bf16x8 a  = *(const bf16x8*)(hrow + koff);
            bf16x8 bb = *(const bf16x8*)(wrow + koff);
            acc = __builtin_amdgcn_mfma_f32_16x16x32_bf16(a, bb, acc, 0, 0, 0);
        }
#pragma unroll
        for (int s = 0; s < 4; ++s) {
            const int a16 = s * 256 + (((l * 4) + w) ^ (l & 7));
            ((float*)red)[(size_t)a16 * 4u] = acc[s];
        }
        __syncthreads();
        float sum = 0.f;
#pragma unroll
        for (int v = 0; v < 4; ++v) {
            const int a16 = w * 256 + (((l * 4) + v) ^ (l & 7));
            sum += ((const float*)red)[(size_t)a16 * 4u];
        }
        const int o = 16 * n + l15;
        const int b = 16 * p + 4 * l4 + w;
        out[((size_t)(t - 1) * 64u + b) * 128u + o] = sum + bout[o];
    }
}

// ============================== launcher ====================================
extern "C" void kernel_launch(void* const* d_in, const int* in_sizes, int n_in,
                              void* d_out, int out_size, void* d_ws, size_t ws_size,
                              hipStream_t stream) {
    const float* in_seq = (const float*)d_in[0];
    const float* h0     = (const float*)d_in[1];
    const float* c0     = (const float*)d_in[2];
    const float* W_ih   = (const float*)d_in[3];
    const float* W_hh   = (const float*)d_in[4];
    const float* b_ih   = (const float*)d_in[5];
    const float* b_hh   = (const float*)d_in[6];
    const float* W_out  = (const float*)d_in[7];
    const float* b_out  = (const float*)d_in[8];
    char* ws = (char*)d_ws;
    float* out = (float*)d_out;

    if (ws_size >= (size_t)PS_TOTAL) {
        // ---------------- persistent path ----------------------------------
        unsigned short* xbf   = (unsigned short*)(ws + PS_XBF);
        unsigned short* wperm = (unsigned short*)(ws + PS_WPERM);
        unsigned short* woutb = (unsigned short*)(ws + PS_WOUT);
        float*          bperm = (float*)(ws + PS_BPERM);
        unsigned short* hring = (unsigned short*)(ws + PS_HRING);
        unsigned int*   done  = (unsigned int*)(ws + PS_FLAGS);

        lstm_prep_ps<<<2048, 256, 0, stream>>>(in_seq, h0, W_ih, W_hh, b_ih, b_hh,
                                               W_out, xbf, wperm, woutb, bperm,
                                               hring, done);
        void* args[] = { &xbf, &wperm, &woutb, &bperm, (void*)&b_out, (void*)&c0,
                         &hring, &done, &out };
        hipLaunchCooperativeKernel((const void*)lstm_persist, dim3(256), dim3(512),
                                   args, 0, stream);
    } else {
        // ---------------- fallback: proven multi-launch path ---------------
        unsigned short* xbf   = (unsigned short*)(ws + OFF_XBF);
        unsigned short* wcat  = (unsigned short*)(ws + OFF_WCAT);
        unsigned short* woutb = (unsigned short*)(ws + OFF_WOUT);
        float*          bsum  = (float*)(ws + OFF_BSUM);
        unsigned short* hbuf  = (unsigned short*)(ws + OFF_HBUF);
        float*          cst   = (float*)(ws + OFF_CST);

        lstm_prep<<<2048, 256, 0, stream>>>(in_seq, h0, c0, W_ih, W_hh, b_ih, b_hh,
                                            W_out, xbf, wcat, woutb, bsum, hbuf, cst);
        for (int t = 0; t <= 1024; ++t) {
            lstm_step<<<288, 256, 0, stream>>>(xbf, wcat, woutb, bsum, b_out,
                                               hbuf, cst, out, t);
        }
    }
}